// Round 5
// baseline (246.887 us; speedup 1.0000x reference)
//
#include <hip/hip_runtime.h>
#include <hip/hip_bf16.h>
#include <math.h>

#define NS 4096          // samples per view
#define NI 8192          // total instances (2 views)
#define DIM 512          // feature dim (= 512 bytes per row in fp8)
#define TEMP_INV 2.0f    // 1/t, t = 0.5
#define NBLK 64          // NI/128 tile blocks per side
#define NTRI (NBLK * (NBLK + 1) / 2)   // 2080 upper-triangle tiles
#define BK 128           // k-elems (bytes) staged per stage

typedef int   v8i __attribute__((ext_vector_type(8)));   // 32 fp8 (8 VGPRs)
typedef int   v4i __attribute__((ext_vector_type(4)));   // 16 fp8
typedef float v4f __attribute__((ext_vector_type(4)));   // 4 fp32 acc

// async global->LDS, 16B per lane. LDS dest is wave-uniform base + lane*16.
__device__ __forceinline__ void gld16(const void* g, void* l) {
    __builtin_amdgcn_global_load_lds(
        (const __attribute__((address_space(1))) void*)g,
        (__attribute__((address_space(3))) void*)l, 16, 0, 0);
}

// ---------------------------------------------------------------------------
// Kernel 1: norms + positive dots (fp32), cast X -> fp8 e4m3; zeros rowsum.
// ---------------------------------------------------------------------------
__global__ __launch_bounds__(256) void prep_kernel(
        const float* __restrict__ x1, const float* __restrict__ x2,
        unsigned char* __restrict__ Xq, float* __restrict__ rnorm,
        float* __restrict__ posdot, float* __restrict__ rowsum) {
    const int t = threadIdx.x;
    if (t < 4) rowsum[blockIdx.x * 4 + t] = 0.f;   // 2048 blocks x 4 = NI
    const int sub = t >> 7;
    const int c4 = t & 127;
    const int i = blockIdx.x * 2 + sub;
    const float4 a = ((const float4*)(x1 + (size_t)i * DIM))[c4];
    const float4 b = ((const float4*)(x2 + (size_t)i * DIM))[c4];
    float s1 = a.x*a.x + a.y*a.y + a.z*a.z + a.w*a.w;
    float s2 = b.x*b.x + b.y*b.y + b.z*b.z + b.w*b.w;
    float dd = a.x*b.x + a.y*b.y + a.z*b.z + a.w*b.w;

    // pack 4 floats -> 4 e4m3 bytes (RNE)
    int pa = __builtin_amdgcn_cvt_pk_fp8_f32(a.x, a.y, 0, false);
    pa     = __builtin_amdgcn_cvt_pk_fp8_f32(a.z, a.w, pa, true);
    int pb = __builtin_amdgcn_cvt_pk_fp8_f32(b.x, b.y, 0, false);
    pb     = __builtin_amdgcn_cvt_pk_fp8_f32(b.z, b.w, pb, true);
    ((int*)(Xq + (size_t)i * DIM))[c4] = pa;
    ((int*)(Xq + (size_t)(i + NS) * DIM))[c4] = pb;

    #pragma unroll
    for (int off = 32; off; off >>= 1) {
        s1 += __shfl_down(s1, off, 64);
        s2 += __shfl_down(s2, off, 64);
        dd += __shfl_down(dd, off, 64);
    }
    __shared__ float red[2][2][3];
    if ((t & 63) == 0) {
        const int w = (t >> 6) & 1;
        red[sub][w][0] = s1; red[sub][w][1] = s2; red[sub][w][2] = dd;
    }
    __syncthreads();
    if ((t & 127) == 0) {
        s1 = red[sub][0][0] + red[sub][1][0];
        s2 = red[sub][0][1] + red[sub][1][1];
        dd = red[sub][0][2] + red[sub][1][2];
        rnorm[i]      = 1.0f / sqrtf(s1);
        rnorm[i + NS] = 1.0f / sqrtf(s2);
        posdot[i] = dd;
    }
}

// ---------------------------------------------------------------------------
// Kernel 2: upper-triangle 128x128 tiles of G = Xq*Xq^T via MX-fp8
// mfma_scale_f32_16x16x128_f8f6f4 with unit scales (0x7F7F7F7F: e8m0=127
// => 1.0 for ANY opsel byte). Single-buffered m97 2-barrier K-loop (4 stages
// of K=128), 16 KB/matrix LDS => 3 blocks/CU. 16B chunk slot = kc^(row&7)
// swizzle: staging stays gld16-contiguous, fragment ds_read_b128 balanced.
// ---------------------------------------------------------------------------
__global__ __launch_bounds__(256, 3) void sim_kernel(
        const unsigned char* __restrict__ Xq, const float* __restrict__ rnorm,
        float* __restrict__ rowsum, float* __restrict__ negpart) {
    // --- triangular decode: id -> (bi, bj), bi<=bj
    const int id = blockIdx.x;
    int bi = (int)((129.0f - sqrtf(16641.0f - 8.0f * (float)id)) * 0.5f);
    int base = bi * (129 - bi) / 2;
    if (id < base)                     { --bi; base = bi * (129 - bi) / 2; }
    else if (id >= base + (64 - bi))   { ++bi; base = bi * (129 - bi) / 2; }
    const int bj = bi + (id - base);
    const bool offdiag = (bj != bi);
    const int i0 = bi * 128, j0 = bj * 128;

    __shared__ unsigned char lA[128 * BK];     // 16 KB
    __shared__ unsigned char lB[128 * BK];     // 16 KB
    __shared__ float sRowAll[2][128];
    __shared__ float sColAll[2][128];
    __shared__ float sNeg[4];

    const int t = threadIdx.x;
    const int lane = t & 63, wv = t >> 6;
    const int wr = wv >> 1, wc = wv & 1;       // 2x2 waves, each 64x64
    const int r16 = lane & 15, quad = lane >> 4;

    // --- staging: per wave 4 A + 4 B gld16 per stage; 1024 16B chunks/matrix.
    // lin = chunk id; row = lin>>3; slot cs = lin&7 holds global kc = cs^(row&7)
    int gOffA[4], gOffB[4], lOff[4];
    #pragma unroll
    for (int q = 0; q < 4; ++q) {
        const int lin = (wv * 4 + q) * 64 + lane;
        const int row = lin >> 3, cs = lin & 7;
        const int kc = cs ^ (row & 7);
        gOffA[q] = (i0 + row) * DIM + kc * 16;
        gOffB[q] = (j0 + row) * DIM + kc * 16;
        lOff[q] = (wv * 4 + q) * 1024;         // bytes; HW adds lane*16
    }

    // --- fragment LDS byte offsets: lane needs kc = quad*2, quad*2+1 of its row
    int offA0[4], offA1[4], offB0[4], offB1[4];
    #pragma unroll
    for (int tt = 0; tt < 4; ++tt) {
        const int tra = wr * 64 + tt * 16 + r16;
        offA0[tt] = tra * BK + (((quad * 2)     ^ (tra & 7)) * 16);
        offA1[tt] = tra * BK + (((quad * 2 + 1) ^ (tra & 7)) * 16);
        const int trb = wc * 64 + tt * 16 + r16;
        offB0[tt] = trb * BK + (((quad * 2)     ^ (trb & 7)) * 16);
        offB1[tt] = trb * BK + (((quad * 2 + 1) ^ (trb & 7)) * 16);
    }

    v4f acc[4][4];
    #pragma unroll
    for (int a = 0; a < 4; ++a)
        #pragma unroll
        for (int b = 0; b < 4; ++b)
            acc[a][b] = (v4f){0.f, 0.f, 0.f, 0.f};

    const int usc = 0x7F7F7F7F;                // unit scales, opsel-immune

    #pragma unroll
    for (int s = 0; s < DIM / BK; ++s) {       // 4 stages
        __syncthreads();                       // reads of prior stage done
        const int k0 = s * BK;
        #pragma unroll
        for (int q = 0; q < 4; ++q) {
            gld16(Xq + gOffA[q] + k0, lA + lOff[q]);
            gld16(Xq + gOffB[q] + k0, lB + lOff[q]);
        }
        __syncthreads();                       // vmcnt(0) drain + barrier

        v8i bf[4];
        #pragma unroll
        for (int tt = 0; tt < 4; ++tt) {
            const v4i lo = *(const v4i*)(lB + offB0[tt]);
            const v4i hi = *(const v4i*)(lB + offB1[tt]);
            bf[tt] = __builtin_shufflevector(lo, hi, 0, 1, 2, 3, 4, 5, 6, 7);
        }
        #pragma unroll
        for (int ta = 0; ta < 4; ++ta) {
            const v4i lo = *(const v4i*)(lA + offA0[ta]);
            const v4i hi = *(const v4i*)(lA + offA1[ta]);
            const v8i af = __builtin_shufflevector(lo, hi, 0, 1, 2, 3, 4, 5, 6, 7);
            #pragma unroll
            for (int tb = 0; tb < 4; ++tb)
                acc[ta][tb] = __builtin_amdgcn_mfma_scale_f32_16x16x128_f8f6f4(
                    af, bf[tb], acc[ta][tb], 0, 0, 0, usc, 0, usc);
        }
    }

    // --- epilogue: sim2 = 2*D*r_i*r_j; masked (j==i, j==i^NS) -> exp gives 1
    float rc[4];
    int colg[4];
    #pragma unroll
    for (int tb = 0; tb < 4; ++tb) {
        colg[tb] = j0 + wc * 64 + tb * 16 + r16;
        rc[tb] = rnorm[colg[tb]];
    }
    float negacc = 0.f;
    float colacc[4] = {0.f, 0.f, 0.f, 0.f};
    #pragma unroll
    for (int ta = 0; ta < 4; ++ta) {
        #pragma unroll
        for (int r = 0; r < 4; ++r) {
            const int rowl = wr * 64 + ta * 16 + quad * 4 + r;
            const int rowg = i0 + rowl;
            const float rr = rnorm[rowg] * TEMP_INV;
            float rowe = 0.f;
            #pragma unroll
            for (int tb = 0; tb < 4; ++tb) {
                const float sim2 = acc[ta][tb][r] * rr * rc[tb];
                const bool masked = (colg[tb] == rowg) || (colg[tb] == (rowg ^ NS));
                const float e = masked ? 1.0f : __expf(sim2);
                rowe   += e;
                negacc += masked ? 0.0f : sim2;
                colacc[tb] += e;
            }
            #pragma unroll
            for (int off = 1; off < 16; off <<= 1)
                rowe += __shfl_xor(rowe, off, 64);
            if (r16 == 0) sRowAll[wc][rowl] = rowe;
        }
    }
    #pragma unroll
    for (int tb = 0; tb < 4; ++tb) {
        colacc[tb] += __shfl_xor(colacc[tb], 16, 64);
        colacc[tb] += __shfl_xor(colacc[tb], 32, 64);
        if (quad == 0) sColAll[wr][wc * 64 + tb * 16 + r16] = colacc[tb];
    }
    if (offdiag) negacc *= 2.0f;
    #pragma unroll
    for (int off = 1; off < 64; off <<= 1)
        negacc += __shfl_xor(negacc, off, 64);
    if (lane == 0) sNeg[wv] = negacc;

    __syncthreads();

    if (t < 128) {
        atomicAdd(&rowsum[i0 + t], sRowAll[0][t] + sRowAll[1][t]);
        if (offdiag)
            atomicAdd(&rowsum[j0 + t], sColAll[0][t] + sColAll[1][t]);
    }
    if (t == 0)
        negpart[id] = sNeg[0] + sNeg[1] + sNeg[2] + sNeg[3];
}

// ---------------------------------------------------------------------------
// Kernel 3: final scalars. E_i = rowsum[i] (includes +2 from masked entries).
// ---------------------------------------------------------------------------
__global__ __launch_bounds__(1024) void final_kernel(
        const float* __restrict__ rowsum, const float* __restrict__ rnorm,
        const float* __restrict__ posdot, const float* __restrict__ negpart,
        float* __restrict__ out) {
    const int t = threadIdx.x;
    float lsum = 0.f, psum = 0.f, nsum = 0.f;
    #pragma unroll
    for (int i = t; i < NI; i += 1024) {
        const int s = i & (NS - 1);
        const float sp = posdot[s] * rnorm[i] * rnorm[i ^ NS] * TEMP_INV;
        const float E = rowsum[i];
        lsum += logf(expf(sp) + E) - sp;
        psum += sp;
    }
    for (int i = t; i < NTRI; i += 1024)
        nsum += negpart[i];
    __shared__ float red[3][16];
    #pragma unroll
    for (int off = 32; off; off >>= 1) {
        lsum += __shfl_down(lsum, off, 64);
        psum += __shfl_down(psum, off, 64);
        nsum += __shfl_down(nsum, off, 64);
    }
    if ((t & 63) == 0) {
        red[0][t >> 6] = lsum; red[1][t >> 6] = psum; red[2][t >> 6] = nsum;
    }
    __syncthreads();
    if (t == 0) {
        lsum = 0.f; psum = 0.f; nsum = 0.f;
        #pragma unroll
        for (int w = 0; w < 16; ++w) {
            lsum += red[0][w]; psum += red[1][w]; nsum += red[2][w];
        }
        out[0] = lsum / (float)NI;
        out[1] = psum / (float)NI;
        out[2] = nsum / ((float)NI * (float)(NI - 2));
    }
}

// ---------------------------------------------------------------------------
extern "C" void kernel_launch(void* const* d_in, const int* in_sizes, int n_in,
                              void* d_out, int out_size, void* d_ws, size_t ws_size,
                              hipStream_t stream) {
    const float* x1 = (const float*)d_in[0];
    const float* x2 = (const float*)d_in[1];
    float* out = (float*)d_out;

    char* ws = (char*)d_ws;
    unsigned char* Xq = (unsigned char*)ws;                   // NI*DIM = 4 MB
    float* rnorm  = (float*)(ws + (size_t)NI * DIM);          // NI
    float* posdot = rnorm + NI;                               // NS
    float* rowsum = posdot + NS;                              // NI (zeroed in prep)
    float* negpart = rowsum + NI;                             // NTRI (all written)

    prep_kernel<<<NS / 2, 256, 0, stream>>>(x1, x2, Xq, rnorm, posdot, rowsum);

    sim_kernel<<<NTRI, 256, 0, stream>>>(Xq, rnorm, rowsum, negpart);

    final_kernel<<<1, 1024, 0, stream>>>(rowsum, rnorm, posdot, negpart, out);
}

// Round 6
// 145.455 us; speedup vs baseline: 1.6973x; 1.6973x over previous
//
#include <hip/hip_runtime.h>
#include <hip/hip_bf16.h>
#include <math.h>

#define NS 4096          // samples per view
#define NI 8192          // total instances (2 views)
#define DIM 512          // feature dim (= 512 bytes per row in fp8)
#define TEMP_INV 2.0f    // 1/t, t = 0.5
#define NBLK 64          // NI/128 tile blocks per side
#define NTRI (NBLK * (NBLK + 1) / 2)   // 2080 upper-triangle tiles
#define BK 128           // k-bytes staged per stage

typedef int   v8i __attribute__((ext_vector_type(8)));   // 32 fp8 (8 VGPRs)
typedef float v4f __attribute__((ext_vector_type(4)));   // 4 fp32 acc

// async global->LDS, 16B per lane. LDS dest is wave-uniform base + lane*16.
__device__ __forceinline__ void gld16(const void* g, void* l) {
    __builtin_amdgcn_global_load_lds(
        (const __attribute__((address_space(1))) void*)g,
        (__attribute__((address_space(3))) void*)l, 16, 0, 0);
}

// ---------------------------------------------------------------------------
// Kernel 1: norms + positive dots (fp32), cast X -> fp8 e4m3; zeros rowsum.
// ---------------------------------------------------------------------------
__global__ __launch_bounds__(256) void prep_kernel(
        const float* __restrict__ x1, const float* __restrict__ x2,
        unsigned char* __restrict__ Xq, float* __restrict__ rnorm,
        float* __restrict__ posdot, float* __restrict__ rowsum) {
    const int t = threadIdx.x;
    if (t < 4) rowsum[blockIdx.x * 4 + t] = 0.f;   // 2048 blocks x 4 = NI
    const int sub = t >> 7;
    const int c4 = t & 127;
    const int i = blockIdx.x * 2 + sub;
    const float4 a = ((const float4*)(x1 + (size_t)i * DIM))[c4];
    const float4 b = ((const float4*)(x2 + (size_t)i * DIM))[c4];
    float s1 = a.x*a.x + a.y*a.y + a.z*a.z + a.w*a.w;
    float s2 = b.x*b.x + b.y*b.y + b.z*b.z + b.w*b.w;
    float dd = a.x*b.x + a.y*b.y + a.z*b.z + a.w*b.w;

    // pack 4 floats -> 4 e4m3 bytes (RNE)
    int pa = __builtin_amdgcn_cvt_pk_fp8_f32(a.x, a.y, 0, false);
    pa     = __builtin_amdgcn_cvt_pk_fp8_f32(a.z, a.w, pa, true);
    int pb = __builtin_amdgcn_cvt_pk_fp8_f32(b.x, b.y, 0, false);
    pb     = __builtin_amdgcn_cvt_pk_fp8_f32(b.z, b.w, pb, true);
    ((int*)(Xq + (size_t)i * DIM))[c4] = pa;
    ((int*)(Xq + (size_t)(i + NS) * DIM))[c4] = pb;

    #pragma unroll
    for (int off = 32; off; off >>= 1) {
        s1 += __shfl_down(s1, off, 64);
        s2 += __shfl_down(s2, off, 64);
        dd += __shfl_down(dd, off, 64);
    }
    __shared__ float red[2][2][3];
    if ((t & 63) == 0) {
        const int w = (t >> 6) & 1;
        red[sub][w][0] = s1; red[sub][w][1] = s2; red[sub][w][2] = dd;
    }
    __syncthreads();
    if ((t & 127) == 0) {
        s1 = red[sub][0][0] + red[sub][1][0];
        s2 = red[sub][0][1] + red[sub][1][1];
        dd = red[sub][0][2] + red[sub][1][2];
        rnorm[i]      = 1.0f / sqrtf(s1);
        rnorm[i + NS] = 1.0f / sqrtf(s2);
        posdot[i] = dd;
    }
}

// ---------------------------------------------------------------------------
// Kernel 2: upper-triangle 128x128 tiles of G = Xq*Xq^T via MX-fp8
// mfma_scale_f32_16x16x128_f8f6f4, unit scales (0x7F7F7F7F, opsel-immune).
// LDS layout: row stride 128B = 8 x 16B slots; slot = kc ^ (((row>>1)&3)<<1)
// (even-bit XOR only => each lane's logical 32B k-block stays contiguous &
// natural-order => direct v8i load, no shufflevector; fully compensated at
// read so the logical layout is identical to the round-5-verified one).
// NO min-waves launch-bound clamp (round-5 spill trigger).
// ---------------------------------------------------------------------------
__global__ __launch_bounds__(256) void sim_kernel(
        const unsigned char* __restrict__ Xq, const float* __restrict__ rnorm,
        float* __restrict__ rowsum, float* __restrict__ negpart) {
    // --- triangular decode: id -> (bi, bj), bi<=bj
    const int id = blockIdx.x;
    int bi = (int)((129.0f - sqrtf(16641.0f - 8.0f * (float)id)) * 0.5f);
    int base = bi * (129 - bi) / 2;
    if (id < base)                     { --bi; base = bi * (129 - bi) / 2; }
    else if (id >= base + (64 - bi))   { ++bi; base = bi * (129 - bi) / 2; }
    const int bj = bi + (id - base);
    const bool offdiag = (bj != bi);
    const int i0 = bi * 128, j0 = bj * 128;

    __shared__ unsigned char lA[128 * BK];     // 16 KB
    __shared__ unsigned char lB[128 * BK];     // 16 KB
    __shared__ float sRowAll[2][128];
    __shared__ float sColAll[2][128];
    __shared__ float sNeg[4];

    const int t = threadIdx.x;
    const int lane = t & 63, wv = t >> 6;
    const int wr = wv >> 1, wc = wv & 1;       // 2x2 waves, each 64x64
    const int r16 = lane & 15, quad = lane >> 4;

    // --- staging: per wave 4 A + 4 B gld16 per stage; 1024 16B chunks/matrix.
    // lane writes physical slot cs=lin&7 of row=lin>>3; content = global
    // k-chunk kc = cs ^ (((row>>1)&3)<<1)
    int gOffA[4], gOffB[4], lOff[4];
    #pragma unroll
    for (int q = 0; q < 4; ++q) {
        const int lin = (wv * 4 + q) * 64 + lane;
        const int row = lin >> 3, cs = lin & 7;
        const int kc = cs ^ (((row >> 1) & 3) << 1);
        gOffA[q] = (i0 + row) * DIM + kc * 16;
        gOffB[q] = (j0 + row) * DIM + kc * 16;
        lOff[q] = (wv * 4 + q) * 1024;         // bytes; HW adds lane*16
    }

    // --- fragment LDS byte offsets: lane's logical k-block {2q,2q+1} lives
    // at 32B block (quad ^ ((row>>1)&3)), natural half order.
    int offA[4], offB[4];
    #pragma unroll
    for (int tt = 0; tt < 4; ++tt) {
        const int tra = wr * 64 + tt * 16 + r16;
        offA[tt] = tra * BK + ((quad ^ ((tra >> 1) & 3)) * 32);
        const int trb = wc * 64 + tt * 16 + r16;
        offB[tt] = trb * BK + ((quad ^ ((trb >> 1) & 3)) * 32);
    }

    v4f acc[4][4];
    #pragma unroll
    for (int a = 0; a < 4; ++a)
        #pragma unroll
        for (int b = 0; b < 4; ++b)
            acc[a][b] = (v4f){0.f, 0.f, 0.f, 0.f};

    const int usc = 0x7F7F7F7F;                // unit scales, opsel-immune

    #pragma unroll
    for (int s = 0; s < DIM / BK; ++s) {       // 4 stages
        __syncthreads();                       // reads of prior stage done
        const int k0 = s * BK;
        #pragma unroll
        for (int q = 0; q < 4; ++q) {
            gld16(Xq + gOffA[q] + k0, lA + lOff[q]);
            gld16(Xq + gOffB[q] + k0, lB + lOff[q]);
        }
        __syncthreads();                       // vmcnt(0) drain + barrier

        v8i bf[4];
        #pragma unroll
        for (int tt = 0; tt < 4; ++tt)
            bf[tt] = *(const v8i*)(lB + offB[tt]);
        #pragma unroll
        for (int ta = 0; ta < 4; ++ta) {
            const v8i af = *(const v8i*)(lA + offA[ta]);
            #pragma unroll
            for (int tb = 0; tb < 4; ++tb)
                acc[ta][tb] = __builtin_amdgcn_mfma_scale_f32_16x16x128_f8f6f4(
                    af, bf[tb], acc[ta][tb], 0, 0, 0, usc, 0, usc);
        }
    }

    // --- epilogue: sim2 = 2*D*r_i*r_j; masked (j==i, j==i^NS) -> exp gives 1
    float rc[4];
    int colg[4];
    #pragma unroll
    for (int tb = 0; tb < 4; ++tb) {
        colg[tb] = j0 + wc * 64 + tb * 16 + r16;
        rc[tb] = rnorm[colg[tb]];
    }
    float negacc = 0.f;
    float colacc[4] = {0.f, 0.f, 0.f, 0.f};
    #pragma unroll
    for (int ta = 0; ta < 4; ++ta) {
        #pragma unroll
        for (int r = 0; r < 4; ++r) {
            const int rowl = wr * 64 + ta * 16 + quad * 4 + r;
            const int rowg = i0 + rowl;
            const float rr = rnorm[rowg] * TEMP_INV;
            float rowe = 0.f;
            #pragma unroll
            for (int tb = 0; tb < 4; ++tb) {
                const float sim2 = acc[ta][tb][r] * rr * rc[tb];
                const bool masked = (colg[tb] == rowg) || (colg[tb] == (rowg ^ NS));
                const float e = masked ? 1.0f : __expf(sim2);
                rowe   += e;
                negacc += masked ? 0.0f : sim2;
                colacc[tb] += e;
            }
            #pragma unroll
            for (int off = 1; off < 16; off <<= 1)
                rowe += __shfl_xor(rowe, off, 64);
            if (r16 == 0) sRowAll[wc][rowl] = rowe;
        }
    }
    #pragma unroll
    for (int tb = 0; tb < 4; ++tb) {
        colacc[tb] += __shfl_xor(colacc[tb], 16, 64);
        colacc[tb] += __shfl_xor(colacc[tb], 32, 64);
        if (quad == 0) sColAll[wr][wc * 64 + tb * 16 + r16] = colacc[tb];
    }
    if (offdiag) negacc *= 2.0f;
    #pragma unroll
    for (int off = 1; off < 64; off <<= 1)
        negacc += __shfl_xor(negacc, off, 64);
    if (lane == 0) sNeg[wv] = negacc;

    __syncthreads();

    if (t < 128) {
        atomicAdd(&rowsum[i0 + t], sRowAll[0][t] + sRowAll[1][t]);
        if (offdiag)
            atomicAdd(&rowsum[j0 + t], sColAll[0][t] + sColAll[1][t]);
    }
    if (t == 0)
        negpart[id] = sNeg[0] + sNeg[1] + sNeg[2] + sNeg[3];
}

// ---------------------------------------------------------------------------
// Kernel 3: final scalars. E_i = rowsum[i] (includes +2 from masked entries).
// ---------------------------------------------------------------------------
__global__ __launch_bounds__(1024) void final_kernel(
        const float* __restrict__ rowsum, const float* __restrict__ rnorm,
        const float* __restrict__ posdot, const float* __restrict__ negpart,
        float* __restrict__ out) {
    const int t = threadIdx.x;
    float lsum = 0.f, psum = 0.f, nsum = 0.f;
    #pragma unroll
    for (int i = t; i < NI; i += 1024) {
        const int s = i & (NS - 1);
        const float sp = posdot[s] * rnorm[i] * rnorm[i ^ NS] * TEMP_INV;
        const float E = rowsum[i];
        lsum += logf(expf(sp) + E) - sp;
        psum += sp;
    }
    for (int i = t; i < NTRI; i += 1024)
        nsum += negpart[i];
    __shared__ float red[3][16];
    #pragma unroll
    for (int off = 32; off; off >>= 1) {
        lsum += __shfl_down(lsum, off, 64);
        psum += __shfl_down(psum, off, 64);
        nsum += __shfl_down(nsum, off, 64);
    }
    if ((t & 63) == 0) {
        red[0][t >> 6] = lsum; red[1][t >> 6] = psum; red[2][t >> 6] = nsum;
    }
    __syncthreads();
    if (t == 0) {
        lsum = 0.f; psum = 0.f; nsum = 0.f;
        #pragma unroll
        for (int w = 0; w < 16; ++w) {
            lsum += red[0][w]; psum += red[1][w]; nsum += red[2][w];
        }
        out[0] = lsum / (float)NI;
        out[1] = psum / (float)NI;
        out[2] = nsum / ((float)NI * (float)(NI - 2));
    }
}

// ---------------------------------------------------------------------------
extern "C" void kernel_launch(void* const* d_in, const int* in_sizes, int n_in,
                              void* d_out, int out_size, void* d_ws, size_t ws_size,
                              hipStream_t stream) {
    const float* x1 = (const float*)d_in[0];
    const float* x2 = (const float*)d_in[1];
    float* out = (float*)d_out;

    char* ws = (char*)d_ws;
    unsigned char* Xq = (unsigned char*)ws;                   // NI*DIM = 4 MB
    float* rnorm  = (float*)(ws + (size_t)NI * DIM);          // NI
    float* posdot = rnorm + NI;                               // NS
    float* rowsum = posdot + NS;                              // NI (zeroed in prep)
    float* negpart = rowsum + NI;                             // NTRI (all written)

    prep_kernel<<<NS / 2, 256, 0, stream>>>(x1, x2, Xq, rnorm, posdot, rowsum);

    sim_kernel<<<NTRI, 256, 0, stream>>>(Xq, rnorm, rowsum, negpart);

    final_kernel<<<1, 1024, 0, stream>>>(rowsum, rnorm, posdot, negpart, out);
}